// Round 8
// baseline (480.960 us; speedup 1.0000x reference)
//
#include <hip/hip_runtime.h>
#include <hip/hip_bf16.h>

// Problem constants
#define NN 50000
#define EE 800000
#define NFR 513
#define NMEL 128
#define HC 128      // H*C = 4*32

typedef __bf16 bf16x8 __attribute__((ext_vector_type(8)));
typedef float floatx4 __attribute__((ext_vector_type(4)));

__device__ __forceinline__ unsigned short f2b(float f) {   // RNE fp32->bf16 bits
    unsigned u = __float_as_uint(f);
    u = (u + 0x7FFFu + ((u >> 16) & 1u)) >> 16;
    return (unsigned short)u;
}
__device__ __forceinline__ float b2f(unsigned short s) {
    return __uint_as_float(((unsigned)s) << 16);
}
__device__ __forceinline__ float lexp(float a) {           // exp(leaky_relu(a, 0.2))
    a = a > 0.f ? a : 0.2f * a;
    return __expf(a);
}

__device__ __forceinline__ float ldf(const float* p, long i) { return p[i]; }
__device__ __forceinline__ void stf(float* p, long i, float v) { p[i] = v; }
__device__ __forceinline__ void stf(__hip_bfloat16* p, long i, float v) {
    ((unsigned short*)p)[i] = f2b(v);
}

// ---------------- fp32 vector GEMM (only for tiny fb@Wg). EPI=2: store bf16 transposed, stride 544 ----------------
#define BM 64
#define BN 64
#define BK 16

template<int EPI, typename TA, typename TB, typename TC>
__global__ __launch_bounds__(256) void gemm_k(const TA* __restrict__ A, const TB* __restrict__ B,
                                              TC* __restrict__ C, int M, int Nn, int K,
                                              const float* __restrict__ bias)
{
    __shared__ float As[BK][BM + 4];
    __shared__ float Bs[BK][BN + 4];
    const int t = threadIdx.x;
    const int row0 = blockIdx.x * BM;
    const int col0 = blockIdx.y * BN;
    const int tc = t & 15, tr = t >> 4;
    float acc[4][4] = {};

    for (int kb = 0; kb < K; kb += BK) {
        #pragma unroll
        for (int i = 0; i < 4; ++i) {
            int idx = i * 256 + t;
            int r = idx >> 4, k = idx & 15;
            int gr = row0 + r, gk = kb + k;
            float v = 0.f;
            if (gr < M && gk < K) v = ldf(A, (long)gr * K + gk);
            As[k][r] = v;
        }
        #pragma unroll
        for (int i = 0; i < 4; ++i) {
            int idx = i * 256 + t;
            int c = idx & 63, k = idx >> 6;
            int gk = kb + k, gc = col0 + c;
            float v = 0.f;
            if (gk < K && gc < Nn) v = ldf(B, (long)gk * Nn + gc);
            Bs[k][c] = v;
        }
        __syncthreads();
        #pragma unroll
        for (int kk = 0; kk < BK; ++kk) {
            float4 av = *reinterpret_cast<const float4*>(&As[kk][tr << 2]);
            float4 bv = *reinterpret_cast<const float4*>(&Bs[kk][tc << 2]);
            float a[4] = {av.x, av.y, av.z, av.w};
            float b[4] = {bv.x, bv.y, bv.z, bv.w};
            #pragma unroll
            for (int i = 0; i < 4; ++i)
                #pragma unroll
                for (int j = 0; j < 4; ++j)
                    acc[i][j] += a[i] * b[j];
        }
        __syncthreads();
    }

    #pragma unroll
    for (int i = 0; i < 4; ++i) {
        int gr = row0 + (tr << 2) + i;
        if (gr >= M) continue;
        #pragma unroll
        for (int j = 0; j < 4; ++j) {
            int gc = col0 + (tc << 2) + j;
            if (gc >= Nn) continue;
            float v = acc[i][j];
            if (EPI == 2) {
                stf(C, (long)gc * 544 + gr, v);      // transposed bf16, zero-padded stride
            } else {
                if (EPI == 1) { v += bias[gc]; v = v > 0.f ? v : 0.01f * v; }
                stf(C, (long)gr * Nn + gc, v);
            }
        }
    }
}

// ---------------- transpose-convert: out[n*KP+k] = bf16(in[k*N+n]) ----------------
__global__ void k_trans(const float* __restrict__ in, __hip_bfloat16* __restrict__ outp,
                        int K, int N, int KP)
{
    int id = blockIdx.x * 256 + threadIdx.x;
    if (id >= N * KP) return;
    int n = id / KP, k = id % KP;
    float v = (k < K) ? in[(long)k * N + n] : 0.f;
    ((unsigned short*)outp)[id] = f2b(v);
}

// ---------------- barrier-free strip GEMM: wave = 16 rows x (NT*16) cols, no LDS ----------------
// A fp32 (guarded, converted in regs) or bf16 (16B-aligned rows); Bt bf16 [Nn][KB].
// Fragment maps (verified m89/m91): A[m=lane&15][k=quad*8+j]; B[n=lane&15][k=quad*8+j];
// D row=quad*4+reg, col=lane&15.

__device__ __forceinline__ bf16x8 loadA8(const float* A, long row, int K, int k0)
{
    const float* ap = A + row * (long)K + k0;
    float f[8];
    if (k0 + 8 <= K) {
        #pragma unroll
        for (int j = 0; j < 8; ++j) f[j] = ap[j];
    } else {
        #pragma unroll
        for (int j = 0; j < 8; ++j) f[j] = (k0 + j < K) ? ap[j] : 0.f;
    }
    union { bf16x8 v; unsigned short u[8]; } t;
    #pragma unroll
    for (int j = 0; j < 8; ++j) t.u[j] = f2b(f[j]);
    return t.v;
}
__device__ __forceinline__ bf16x8 loadA8(const __hip_bfloat16* A, long row, int K, int k0)
{
    return *reinterpret_cast<const bf16x8*>((const unsigned short*)A + row * (long)K + k0);
}

template<int NT, int EPI, typename TA>
__global__ __launch_bounds__(256) void sgemm(const TA* __restrict__ A,
                                             const __hip_bfloat16* __restrict__ Bt,
                                             __hip_bfloat16* __restrict__ C,
                                             int M, int K, int KB,
                                             const float* __restrict__ bias)
{
    const int lane = threadIdx.x & 63;
    const long wid = (long)blockIdx.x * 4 + (threadIdx.x >> 6);
    const long m0 = wid * 16;
    if (m0 >= M) return;
    const int lm = lane & 15, kq = lane >> 4;
    constexpr int Nc = NT * 16;

    floatx4 acc[NT];
    #pragma unroll
    for (int j = 0; j < NT; ++j) acc[j] = 0.f;

    const unsigned short* bp = (const unsigned short*)Bt + (long)lm * KB;

    const int KCH = KB / 32;
    for (int kc = 0; kc < KCH; ++kc) {
        int k0 = kc * 32 + kq * 8;
        bf16x8 af = loadA8(A, m0 + lm, K, k0);
        #pragma unroll
        for (int j = 0; j < NT; ++j) {
            bf16x8 bfj = *reinterpret_cast<const bf16x8*>(bp + (long)j * 16 * KB + k0);
            acc[j] = __builtin_amdgcn_mfma_f32_16x16x32_bf16(af, bfj, acc[j], 0, 0, 0);
        }
    }

    #pragma unroll
    for (int j = 0; j < NT; ++j) {
        int gc = j * 16 + lm;
        float bj = (EPI == 1) ? bias[gc] : 0.f;
        #pragma unroll
        for (int r = 0; r < 4; ++r) {
            long gr = m0 + kq * 4 + r;
            float v = acc[j][r];
            if (EPI == 1) { v += bj; v = v > 0.f ? v : 0.01f * v; }
            ((unsigned short*)C)[gr * Nc + gc] = f2b(v);
        }
    }
}

// ---------------- per-node attention coefficients (h in bf16) ----------------
__global__ void k_att(const __hip_bfloat16* __restrict__ h, const float* __restrict__ att_src,
                      const float* __restrict__ att_dst,
                      float* __restrict__ a_s, float* __restrict__ a_d)
{
    int id = blockIdx.x * blockDim.x + threadIdx.x;
    if (id >= NN * 4) return;
    int n = id >> 2, hh = id & 3;
    const unsigned short* hr = (const unsigned short*)(h + (long)n * HC + hh * 32);
    float s1 = 0.f, s2 = 0.f;
    #pragma unroll
    for (int c = 0; c < 32; ++c) {
        float v = b2f(hr[c]);
        s1 += v * att_src[hh * 32 + c];
        s2 += v * att_dst[hh * 32 + c];
    }
    a_s[id] = s1;
    a_d[id] = s2;
}

// ---------------- CSR build: histogram -> scan -> fill ----------------
__global__ void k_hist(const int* __restrict__ ei, int* __restrict__ hist)
{
    int e = blockIdx.x * 256 + threadIdx.x;
    if (e < EE) atomicAdd(&hist[ei[EE + e]], 1);
}

__global__ __launch_bounds__(512) void k_scan1(const int* __restrict__ hist, int* __restrict__ start,
                                               int* __restrict__ aux)
{
    __shared__ int sm[512];
    int t = threadIdx.x, i = blockIdx.x * 512 + t;
    int v = (i < NN) ? hist[i] : 0;
    sm[t] = v;
    __syncthreads();
    for (int off = 1; off < 512; off <<= 1) {
        int x = (t >= off) ? sm[t - off] : 0;
        __syncthreads();
        sm[t] += x;
        __syncthreads();
    }
    if (i < NN) start[i] = sm[t] - v;   // exclusive
    if (t == 511) aux[blockIdx.x] = sm[511];
}

// parallel exclusive scan of the 98 block sums (was a serial 1-thread loop)
__global__ __launch_bounds__(128) void k_scan2(int* __restrict__ aux, int nb)
{
    __shared__ int sm[128];
    int t = threadIdx.x;
    int v = (t < nb) ? aux[t] : 0;
    sm[t] = v;
    __syncthreads();
    for (int off = 1; off < 128; off <<= 1) {
        int x = (t >= off) ? sm[t - off] : 0;
        __syncthreads();
        sm[t] += x;
        __syncthreads();
    }
    if (t < nb) aux[t] = sm[t] - v;     // exclusive
}

__global__ __launch_bounds__(512) void k_scan3(int* __restrict__ start, int* __restrict__ cursor,
                                               const int* __restrict__ aux)
{
    int i = blockIdx.x * 512 + threadIdx.x;
    if (i < NN) {
        int v = start[i] + aux[blockIdx.x];
        start[i] = v;
        cursor[i] = v;
    }
    if (i == 0) start[NN] = EE;
}

__global__ void k_fill(const int* __restrict__ ei, int* __restrict__ cursor, int* __restrict__ sorted)
{
    int e = blockIdx.x * 256 + threadIdx.x;
    if (e >= EE) return;
    int s = ei[e], d = ei[EE + e];
    int pos = atomicAdd(&cursor[d], 1);
    sorted[pos] = s;
}

// ---------------- per-node gather-aggregate, unrolled x4 for memory-level parallelism ----------------
__global__ __launch_bounds__(256) void k_agg(const int* __restrict__ start, const int* __restrict__ sorted,
                                             const float* __restrict__ a_s, const float* __restrict__ a_d,
                                             const __hip_bfloat16* __restrict__ h,
                                             const float* __restrict__ bias_g,
                                             __hip_bfloat16* __restrict__ agg)
{
    int wave = threadIdx.x >> 6;
    int lane = threadIdx.x & 63;
    int d = blockIdx.x * 4 + wave;
    if (d >= NN) return;
    int hh = lane >> 4;                 // head of features 2*lane, 2*lane+1
    float ad = a_d[d * 4 + hh];
    int e0 = start[d], e1 = start[d + 1];

    // self-loop contribution
    float ex = lexp(a_s[d * 4 + hh] + ad);
    unsigned hv = *reinterpret_cast<const unsigned*>(h + (long)d * HC + 2 * lane);
    float acc0 = ex * __uint_as_float(hv << 16);
    float acc1 = ex * __uint_as_float(hv & 0xffff0000u);
    float dsum = ex;

    int e = e0;
    for (; e + 4 <= e1; e += 4) {
        int s0 = sorted[e + 0], s1 = sorted[e + 1], s2 = sorted[e + 2], s3 = sorted[e + 3];
        float as0 = a_s[s0 * 4 + hh], as1 = a_s[s1 * 4 + hh];
        float as2 = a_s[s2 * 4 + hh], as3 = a_s[s3 * 4 + hh];
        unsigned h0 = *reinterpret_cast<const unsigned*>(h + (long)s0 * HC + 2 * lane);
        unsigned h1 = *reinterpret_cast<const unsigned*>(h + (long)s1 * HC + 2 * lane);
        unsigned h2 = *reinterpret_cast<const unsigned*>(h + (long)s2 * HC + 2 * lane);
        unsigned h3 = *reinterpret_cast<const unsigned*>(h + (long)s3 * HC + 2 * lane);
        float x0 = lexp(as0 + ad), x1 = lexp(as1 + ad), x2 = lexp(as2 + ad), x3 = lexp(as3 + ad);
        acc0 += x0 * __uint_as_float(h0 << 16);
        acc1 += x0 * __uint_as_float(h0 & 0xffff0000u);
        acc0 += x1 * __uint_as_float(h1 << 16);
        acc1 += x1 * __uint_as_float(h1 & 0xffff0000u);
        acc0 += x2 * __uint_as_float(h2 << 16);
        acc1 += x2 * __uint_as_float(h2 & 0xffff0000u);
        acc0 += x3 * __uint_as_float(h3 << 16);
        acc1 += x3 * __uint_as_float(h3 & 0xffff0000u);
        dsum += x0 + x1 + x2 + x3;
    }
    for (; e < e1; ++e) {
        int s = sorted[e];
        float xe = lexp(a_s[s * 4 + hh] + ad);
        unsigned hs = *reinterpret_cast<const unsigned*>(h + (long)s * HC + 2 * lane);
        acc0 += xe * __uint_as_float(hs << 16);
        acc1 += xe * __uint_as_float(hs & 0xffff0000u);
        dsum += xe;
    }

    float inv = 1.f / dsum;
    float2 bg = *reinterpret_cast<const float2*>(bias_g + 2 * lane);
    float v0 = acc0 * inv + bg.x;
    float v1 = acc1 * inv + bg.y;
    v0 = v0 > 0.f ? v0 : expm1f(v0);
    v1 = v1 > 0.f ? v1 : expm1f(v1);
    unsigned pk = (unsigned)f2b(v0) | ((unsigned)f2b(v1) << 16);
    *reinterpret_cast<unsigned*>((unsigned short*)agg + (long)d * HC + 2 * lane) = pk;
}

// ---------------- final: leaky(x2@W3+b3) -> softmax -> fp32 out (x2 in bf16) ----------------
__global__ __launch_bounds__(256) void k_final(const __hip_bfloat16* __restrict__ x2, const float* __restrict__ W3,
                                               const float* __restrict__ b3, float* __restrict__ out)
{
    __shared__ float w3s[128 * 10];
    __shared__ float b3s[10];
    int t = threadIdx.x;
    for (int i = t; i < 128 * 10; i += 256) w3s[i] = W3[i];
    if (t < 10) b3s[t] = b3[t];
    __syncthreads();
    int n = blockIdx.x * 256 + t;
    if (n >= NN) return;

    float l[10];
    #pragma unroll
    for (int j = 0; j < 10; ++j) l[j] = b3s[j];
    const uint4* row = reinterpret_cast<const uint4*>(x2 + (long)n * 128);
    #pragma unroll 4
    for (int c8 = 0; c8 < 16; ++c8) {
        uint4 v = row[c8];
        const unsigned w[4] = {v.x, v.y, v.z, v.w};
        #pragma unroll
        for (int u = 0; u < 4; ++u) {
            float f0 = __uint_as_float(w[u] << 16);
            float f1 = __uint_as_float(w[u] & 0xffff0000u);
            const float* wr = &w3s[(c8 * 8 + u * 2) * 10];
            #pragma unroll
            for (int j = 0; j < 10; ++j) l[j] += f0 * wr[j] + f1 * wr[10 + j];
        }
    }
    float m = -1e30f;
    #pragma unroll
    for (int j = 0; j < 10; ++j) {
        float v = l[j];
        v = v > 0.f ? v : 0.01f * v;
        l[j] = v;
        m = fmaxf(m, v);
    }
    float sum = 0.f;
    #pragma unroll
    for (int j = 0; j < 10; ++j) { l[j] = __expf(l[j] - m); sum += l[j]; }
    float inv = 1.f / sum;
    #pragma unroll
    for (int j = 0; j < 10; ++j) out[(long)n * 10 + j] = l[j] * inv;
}

extern "C" void kernel_launch(void* const* d_in, const int* in_sizes, int n_in,
                              void* d_out, int out_size, void* d_ws, size_t ws_size,
                              hipStream_t stream)
{
    const float* x       = (const float*)d_in[0];
    const int*   ei      = (const int*)d_in[1];
    const float* fb      = (const float*)d_in[2];
    const float* Wg      = (const float*)d_in[3];
    const float* bias_g  = (const float*)d_in[4];
    const float* att_src = (const float*)d_in[5];
    const float* att_dst = (const float*)d_in[6];
    const float* W1      = (const float*)d_in[7];
    const float* b1      = (const float*)d_in[8];
    const float* W2      = (const float*)d_in[9];
    const float* b2      = (const float*)d_in[10];
    const float* W3      = (const float*)d_in[11];
    const float* b3      = (const float*)d_in[12];
    float* out = (float*)d_out;
    float* ws = (float*)d_ws;

    // workspace layout (float units) — total 14,167,720 floats = 56.67 MB
    float* a_s = ws + 0;                                        //   200,000 [N,4]
    float* a_d = ws + 200000;                                   //   200,000 [N,4]
    __hip_bfloat16* fbWgT = (__hip_bfloat16*)(ws + 400000);     //   [128][544] bf16 (34,816 f)
    __hip_bfloat16* W1T   = (__hip_bfloat16*)(ws + 434816);     //   [256][128] bf16 (16,384 f)
    __hip_bfloat16* W2T   = (__hip_bfloat16*)(ws + 451200);     //   [128][256] bf16 (16,384 f)
    int* hist   = (int*)(ws + 467584);                          //    50,000 (cursor aliases)
    int* startA = (int*)(ws + 517584);                          //    50,004
    int* aux    = (int*)(ws + 567588);                          //       132
    int* sorted = (int*)(ws + 567720);                          //   800,000
    __hip_bfloat16* hbufB = (__hip_bfloat16*)(ws + 1367720);    //   [N,128] bf16 (3,200,000 f)
    __hip_bfloat16* aggB  = (__hip_bfloat16*)(ws + 4567720);    //   [N,128] bf16 (3,200,000 f)
    __hip_bfloat16* x1B   = (__hip_bfloat16*)(ws + 7767720);    //   [N,256] bf16 (6,400,000 f)
    int* cursor = hist;                                         //   alias (hist dead after scan1)
    __hip_bfloat16* x2B = hbufB;                                //   [N,128] bf16 over dead hbuf
    if (ws_size < (size_t)14167720 * sizeof(float)) return;     //   diagnostic: leaves out zeroed

    // zero fbWgT (for K-pad zeros) .. hist (contiguous region)
    hipMemsetAsync(ws + 400000, 0, (size_t)117584 * sizeof(float), stream);

    // fbWgT = (fb @ Wg)^T as bf16, zero-padded K 513->544
    gemm_k<2, float, float, __hip_bfloat16><<<dim3(9, 2), 256, 0, stream>>>(fb, Wg, fbWgT, NFR, HC, NMEL, nullptr);
    // W1T, W2T: transpose-convert weights
    k_trans<<<128, 256, 0, stream>>>(W1, W1T, 128, 256, 128);
    k_trans<<<128, 256, 0, stream>>>(W2, W2T, 256, 128, 256);

    const int GB = (NN / 16 + 3) / 4;   // 782 blocks of 4 waves (16-row strips)

    // h = x @ fbWg   (strip MFMA, fp32 A converted in regs)  [N,128]
    sgemm<8, 0, float><<<GB, 256, 0, stream>>>(x, fbWgT, hbufB, NN, NFR, 544, nullptr);

    // per-node attention coefficients
    k_att<<<(NN * 4 + 255) / 256, 256, 0, stream>>>(hbufB, att_src, att_dst, a_s, a_d);

    // CSR build
    k_hist<<<(EE + 255) / 256, 256, 0, stream>>>(ei, hist);
    k_scan1<<<98, 512, 0, stream>>>(hist, startA, aux);
    k_scan2<<<1, 128, 0, stream>>>(aux, 98);
    k_scan3<<<98, 512, 0, stream>>>(startA, cursor, aux);
    k_fill<<<(EE + 255) / 256, 256, 0, stream>>>(ei, cursor, sorted);

    // gather-aggregate: softmax + messages + bias + ELU -> agg bf16
    k_agg<<<(NN + 3) / 4, 256, 0, stream>>>(startA, sorted, a_s, a_d, hbufB, bias_g, aggB);

    // x1 = leaky(agg @ W1 + b1)   [N,256] bf16
    sgemm<16, 1, __hip_bfloat16><<<GB, 256, 0, stream>>>(aggB, W1T, x1B, NN, 128, 128, b1);

    // x2 = leaky(x1 @ W2 + b2)    [N,128] bf16 (over dead hbuf)
    sgemm<8, 1, __hip_bfloat16><<<GB, 256, 0, stream>>>(x1B, W2T, x2B, NN, 256, 256, b2);

    // out = softmax(leaky(x2 @ W3 + b3))
    k_final<<<(NN + 255) / 256, 256, 0, stream>>>(x2B, W3, b3, out);
}

// Round 9
// 468.481 us; speedup vs baseline: 1.0266x; 1.0266x over previous
//
#include <hip/hip_runtime.h>
#include <hip/hip_bf16.h>

// Problem constants
#define NN 50000
#define EE 800000
#define NFR 513
#define NMEL 128
#define HC 128      // H*C = 4*32

typedef __bf16 bf16x8 __attribute__((ext_vector_type(8)));
typedef float floatx4 __attribute__((ext_vector_type(4)));

__device__ __forceinline__ unsigned short f2b(float f) {   // RNE fp32->bf16 bits
    unsigned u = __float_as_uint(f);
    u = (u + 0x7FFFu + ((u >> 16) & 1u)) >> 16;
    return (unsigned short)u;
}
__device__ __forceinline__ float b2f(unsigned short s) {
    return __uint_as_float(((unsigned)s) << 16);
}
__device__ __forceinline__ float lexp(float a) {           // exp(leaky_relu(a, 0.2))
    a = a > 0.f ? a : 0.2f * a;
    return __expf(a);
}

__device__ __forceinline__ float ldf(const float* p, long i) { return p[i]; }
__device__ __forceinline__ void stf(float* p, long i, float v) { p[i] = v; }
__device__ __forceinline__ void stf(__hip_bfloat16* p, long i, float v) {
    ((unsigned short*)p)[i] = f2b(v);
}

// ---------------- fp32 vector GEMM (only for tiny fb@Wg). EPI=2: store bf16 transposed, stride 544 ----------------
#define BM 64
#define BN 64
#define BK 16

template<int EPI, typename TA, typename TB, typename TC>
__global__ __launch_bounds__(256) void gemm_k(const TA* __restrict__ A, const TB* __restrict__ B,
                                              TC* __restrict__ C, int M, int Nn, int K,
                                              const float* __restrict__ bias)
{
    __shared__ float As[BK][BM + 4];
    __shared__ float Bs[BK][BN + 4];
    const int t = threadIdx.x;
    const int row0 = blockIdx.x * BM;
    const int col0 = blockIdx.y * BN;
    const int tc = t & 15, tr = t >> 4;
    float acc[4][4] = {};

    for (int kb = 0; kb < K; kb += BK) {
        #pragma unroll
        for (int i = 0; i < 4; ++i) {
            int idx = i * 256 + t;
            int r = idx >> 4, k = idx & 15;
            int gr = row0 + r, gk = kb + k;
            float v = 0.f;
            if (gr < M && gk < K) v = ldf(A, (long)gr * K + gk);
            As[k][r] = v;
        }
        #pragma unroll
        for (int i = 0; i < 4; ++i) {
            int idx = i * 256 + t;
            int c = idx & 63, k = idx >> 6;
            int gk = kb + k, gc = col0 + c;
            float v = 0.f;
            if (gk < K && gc < Nn) v = ldf(B, (long)gk * Nn + gc);
            Bs[k][c] = v;
        }
        __syncthreads();
        #pragma unroll
        for (int kk = 0; kk < BK; ++kk) {
            float4 av = *reinterpret_cast<const float4*>(&As[kk][tr << 2]);
            float4 bv = *reinterpret_cast<const float4*>(&Bs[kk][tc << 2]);
            float a[4] = {av.x, av.y, av.z, av.w};
            float b[4] = {bv.x, bv.y, bv.z, bv.w};
            #pragma unroll
            for (int i = 0; i < 4; ++i)
                #pragma unroll
                for (int j = 0; j < 4; ++j)
                    acc[i][j] += a[i] * b[j];
        }
        __syncthreads();
    }

    #pragma unroll
    for (int i = 0; i < 4; ++i) {
        int gr = row0 + (tr << 2) + i;
        if (gr >= M) continue;
        #pragma unroll
        for (int j = 0; j < 4; ++j) {
            int gc = col0 + (tc << 2) + j;
            if (gc >= Nn) continue;
            float v = acc[i][j];
            if (EPI == 2) {
                stf(C, (long)gc * 544 + gr, v);      // transposed bf16, zero-padded stride
            } else {
                if (EPI == 1) { v += bias[gc]; v = v > 0.f ? v : 0.01f * v; }
                stf(C, (long)gr * Nn + gc, v);
            }
        }
    }
}

// ---------------- transpose-convert: out[n*KP+k] = bf16(in[k*N+n]) ----------------
__global__ void k_trans(const float* __restrict__ in, __hip_bfloat16* __restrict__ outp,
                        int K, int N, int KP)
{
    int id = blockIdx.x * 256 + threadIdx.x;
    if (id >= N * KP) return;
    int n = id / KP, k = id % KP;
    float v = (k < K) ? in[(long)k * N + n] : 0.f;
    ((unsigned short*)outp)[id] = f2b(v);
}

// ---------------- h-GEMM: C[50000,128] = bf16(A_fp32[50000,513]) @ Bt[128,544]^T ----------------
// 64 rows/block (4 waves x 16-row strip), B double-buffered in LDS, A direct-to-reg w/ prefetch.
// Fragment maps (verified m89/m91): A[m=lane&15][k=quad*8+j]; B[n=lane&15][k=quad*8+j];
// D row=quad*4+reg, col=lane&15.
#define HPS 40   // LDS row stride (bf16 units): uniform 2-way banking = free

__device__ __forceinline__ bf16x8 loadA8f(const float* A, long row, int k0)
{
    const float* ap = A + row * (long)NFR + k0;
    float f[8];
    if (k0 + 8 <= NFR) {
        #pragma unroll
        for (int j = 0; j < 8; ++j) f[j] = ap[j];
    } else {
        #pragma unroll
        for (int j = 0; j < 8; ++j) f[j] = (k0 + j < NFR) ? ap[j] : 0.f;
    }
    union { bf16x8 v; unsigned short u[8]; } t;
    #pragma unroll
    for (int j = 0; j < 8; ++j) t.u[j] = f2b(f[j]);
    return t.v;
}

__global__ __launch_bounds__(256) void hgemm(const float* __restrict__ A,
                                             const __hip_bfloat16* __restrict__ Bt,
                                             __hip_bfloat16* __restrict__ C)
{
    __shared__ unsigned short Bs[2][128 * HPS];
    const int t = threadIdx.x;
    const int lane = t & 63;
    const long m0 = (long)blockIdx.x * 64 + (t >> 6) * 16;
    const int lm = lane & 15, kq = lane >> 4;
    long ar = m0 + lm; if (ar > NN - 1) ar = NN - 1;   // clamp (stores guarded)

    // B staging: 512 16B-chunks/buffer; thread handles chunks t and t+256
    const int sn0 = t >> 2,  sk0 = (t & 3) * 8;
    const int sn1 = sn0 + 64, sk1 = sk0;

    floatx4 acc[8];
    #pragma unroll
    for (int j = 0; j < 8; ++j) acc[j] = 0.f;

    // prologue: stage B(0), load A(0)
    uint4 pb0 = *reinterpret_cast<const uint4*>((const unsigned short*)Bt + (long)sn0 * 544 + sk0);
    uint4 pb1 = *reinterpret_cast<const uint4*>((const unsigned short*)Bt + (long)sn1 * 544 + sk1);
    bf16x8 af = loadA8f(A, ar, kq * 8);
    *reinterpret_cast<uint4*>(&Bs[0][sn0 * HPS + sk0]) = pb0;
    *reinterpret_cast<uint4*>(&Bs[0][sn1 * HPS + sk1]) = pb1;
    __syncthreads();

    for (int kc = 0; kc < 17; ++kc) {
        const int cur = kc & 1;
        uint4 nb0, nb1; bf16x8 afn;
        if (kc < 16) {
            int kn = (kc + 1) * 32;
            nb0 = *reinterpret_cast<const uint4*>((const unsigned short*)Bt + (long)sn0 * 544 + kn + sk0);
            nb1 = *reinterpret_cast<const uint4*>((const unsigned short*)Bt + (long)sn1 * 544 + kn + sk1);
            afn = loadA8f(A, ar, kn + kq * 8);
        }
        #pragma unroll
        for (int j = 0; j < 8; ++j) {
            bf16x8 bfj = *reinterpret_cast<const bf16x8*>(&Bs[cur][(j * 16 + lm) * HPS + kq * 8]);
            acc[j] = __builtin_amdgcn_mfma_f32_16x16x32_bf16(af, bfj, acc[j], 0, 0, 0);
        }
        if (kc < 16) {
            *reinterpret_cast<uint4*>(&Bs[cur ^ 1][sn0 * HPS + sk0]) = nb0;
            *reinterpret_cast<uint4*>(&Bs[cur ^ 1][sn1 * HPS + sk1]) = nb1;
            af = afn;
        }
        __syncthreads();
    }

    #pragma unroll
    for (int j = 0; j < 8; ++j) {
        int gc = j * 16 + lm;
        #pragma unroll
        for (int r = 0; r < 4; ++r) {
            long gr = m0 + kq * 4 + r;
            if (gr < NN) ((unsigned short*)C)[gr * HC + gc] = f2b(acc[j][r]);
        }
    }
}

// ---------------- barrier-free strip GEMM (bf16 A, small K): wave = 16 rows x 128 cols ----------------
template<int NT, int EPI>
__global__ __launch_bounds__(256) void sgemm(const __hip_bfloat16* __restrict__ A,
                                             const __hip_bfloat16* __restrict__ Bt,
                                             __hip_bfloat16* __restrict__ C,
                                             int M, int K, const float* __restrict__ bias,
                                             int NcTot)
{
    const int lane = threadIdx.x & 63;
    const long wid = (long)blockIdx.x * 4 + (threadIdx.x >> 6);
    const long m0 = wid * 16;
    if (m0 >= M) return;
    const int col0 = blockIdx.y * (NT * 16);
    const int lm = lane & 15, kq = lane >> 4;

    floatx4 acc[NT];
    #pragma unroll
    for (int j = 0; j < NT; ++j) acc[j] = 0.f;

    const unsigned short* ap = (const unsigned short*)A + (m0 + lm) * (long)K;
    const unsigned short* bp = (const unsigned short*)Bt + (long)(col0 + lm) * K;

    const int KCH = K / 32;
    for (int kc = 0; kc < KCH; ++kc) {
        int k0 = kc * 32 + kq * 8;
        bf16x8 af = *reinterpret_cast<const bf16x8*>(ap + k0);
        #pragma unroll
        for (int j = 0; j < NT; ++j) {
            bf16x8 bfj = *reinterpret_cast<const bf16x8*>(bp + (long)j * 16 * K + k0);
            acc[j] = __builtin_amdgcn_mfma_f32_16x16x32_bf16(af, bfj, acc[j], 0, 0, 0);
        }
    }

    #pragma unroll
    for (int j = 0; j < NT; ++j) {
        int gc = col0 + j * 16 + lm;
        float bj = (EPI == 1) ? bias[gc] : 0.f;
        #pragma unroll
        for (int r = 0; r < 4; ++r) {
            long gr = m0 + kq * 4 + r;
            float v = acc[j][r];
            if (EPI == 1) { v += bj; v = v > 0.f ? v : 0.01f * v; }
            ((unsigned short*)C)[gr * NcTot + gc] = f2b(v);
        }
    }
}

// ---------------- per-node attention coefficients (h in bf16) ----------------
__global__ void k_att(const __hip_bfloat16* __restrict__ h, const float* __restrict__ att_src,
                      const float* __restrict__ att_dst,
                      float* __restrict__ a_s, float* __restrict__ a_d)
{
    int id = blockIdx.x * blockDim.x + threadIdx.x;
    if (id >= NN * 4) return;
    int n = id >> 2, hh = id & 3;
    const unsigned short* hr = (const unsigned short*)(h + (long)n * HC + hh * 32);
    float s1 = 0.f, s2 = 0.f;
    #pragma unroll
    for (int c = 0; c < 32; ++c) {
        float v = b2f(hr[c]);
        s1 += v * att_src[hh * 32 + c];
        s2 += v * att_dst[hh * 32 + c];
    }
    a_s[id] = s1;
    a_d[id] = s2;
}

// ---------------- CSR build: histogram -> scan -> fill ----------------
__global__ void k_hist(const int* __restrict__ ei, int* __restrict__ hist)
{
    int e = blockIdx.x * 256 + threadIdx.x;
    if (e < EE) atomicAdd(&hist[ei[EE + e]], 1);
}

__global__ __launch_bounds__(512) void k_scan1(const int* __restrict__ hist, int* __restrict__ start,
                                               int* __restrict__ aux)
{
    __shared__ int sm[512];
    int t = threadIdx.x, i = blockIdx.x * 512 + t;
    int v = (i < NN) ? hist[i] : 0;
    sm[t] = v;
    __syncthreads();
    for (int off = 1; off < 512; off <<= 1) {
        int x = (t >= off) ? sm[t - off] : 0;
        __syncthreads();
        sm[t] += x;
        __syncthreads();
    }
    if (i < NN) start[i] = sm[t] - v;   // exclusive
    if (t == 511) aux[blockIdx.x] = sm[511];
}

__global__ __launch_bounds__(128) void k_scan2(int* __restrict__ aux, int nb)
{
    __shared__ int sm[128];
    int t = threadIdx.x;
    int v = (t < nb) ? aux[t] : 0;
    sm[t] = v;
    __syncthreads();
    for (int off = 1; off < 128; off <<= 1) {
        int x = (t >= off) ? sm[t - off] : 0;
        __syncthreads();
        sm[t] += x;
        __syncthreads();
    }
    if (t < nb) aux[t] = sm[t] - v;     // exclusive
}

__global__ __launch_bounds__(512) void k_scan3(int* __restrict__ start, int* __restrict__ cursor,
                                               const int* __restrict__ aux)
{
    int i = blockIdx.x * 512 + threadIdx.x;
    if (i < NN) {
        int v = start[i] + aux[blockIdx.x];
        start[i] = v;
        cursor[i] = v;
    }
    if (i == 0) start[NN] = EE;
}

__global__ void k_fill(const int* __restrict__ ei, int* __restrict__ cursor, int* __restrict__ sorted)
{
    int e = blockIdx.x * 256 + threadIdx.x;
    if (e >= EE) return;
    int s = ei[e], d = ei[EE + e];
    int pos = atomicAdd(&cursor[d], 1);
    sorted[pos] = s;
}

// ---------------- per-node gather-aggregate, unrolled x4 for memory-level parallelism ----------------
__global__ __launch_bounds__(256) void k_agg(const int* __restrict__ start, const int* __restrict__ sorted,
                                             const float* __restrict__ a_s, const float* __restrict__ a_d,
                                             const __hip_bfloat16* __restrict__ h,
                                             const float* __restrict__ bias_g,
                                             __hip_bfloat16* __restrict__ agg)
{
    int wave = threadIdx.x >> 6;
    int lane = threadIdx.x & 63;
    int d = blockIdx.x * 4 + wave;
    if (d >= NN) return;
    int hh = lane >> 4;                 // head of features 2*lane, 2*lane+1
    float ad = a_d[d * 4 + hh];
    int e0 = start[d], e1 = start[d + 1];

    // self-loop contribution
    float ex = lexp(a_s[d * 4 + hh] + ad);
    unsigned hv = *reinterpret_cast<const unsigned*>(h + (long)d * HC + 2 * lane);
    float acc0 = ex * __uint_as_float(hv << 16);
    float acc1 = ex * __uint_as_float(hv & 0xffff0000u);
    float dsum = ex;

    int e = e0;
    for (; e + 4 <= e1; e += 4) {
        int s0 = sorted[e + 0], s1 = sorted[e + 1], s2 = sorted[e + 2], s3 = sorted[e + 3];
        float as0 = a_s[s0 * 4 + hh], as1 = a_s[s1 * 4 + hh];
        float as2 = a_s[s2 * 4 + hh], as3 = a_s[s3 * 4 + hh];
        unsigned h0 = *reinterpret_cast<const unsigned*>(h + (long)s0 * HC + 2 * lane);
        unsigned h1 = *reinterpret_cast<const unsigned*>(h + (long)s1 * HC + 2 * lane);
        unsigned h2 = *reinterpret_cast<const unsigned*>(h + (long)s2 * HC + 2 * lane);
        unsigned h3 = *reinterpret_cast<const unsigned*>(h + (long)s3 * HC + 2 * lane);
        float x0 = lexp(as0 + ad), x1 = lexp(as1 + ad), x2 = lexp(as2 + ad), x3 = lexp(as3 + ad);
        acc0 += x0 * __uint_as_float(h0 << 16);
        acc1 += x0 * __uint_as_float(h0 & 0xffff0000u);
        acc0 += x1 * __uint_as_float(h1 << 16);
        acc1 += x1 * __uint_as_float(h1 & 0xffff0000u);
        acc0 += x2 * __uint_as_float(h2 << 16);
        acc1 += x2 * __uint_as_float(h2 & 0xffff0000u);
        acc0 += x3 * __uint_as_float(h3 << 16);
        acc1 += x3 * __uint_as_float(h3 & 0xffff0000u);
        dsum += x0 + x1 + x2 + x3;
    }
    for (; e < e1; ++e) {
        int s = sorted[e];
        float xe = lexp(a_s[s * 4 + hh] + ad);
        unsigned hs = *reinterpret_cast<const unsigned*>(h + (long)s * HC + 2 * lane);
        acc0 += xe * __uint_as_float(hs << 16);
        acc1 += xe * __uint_as_float(hs & 0xffff0000u);
        dsum += xe;
    }

    float inv = 1.f / dsum;
    float2 bg = *reinterpret_cast<const float2*>(bias_g + 2 * lane);
    float v0 = acc0 * inv + bg.x;
    float v1 = acc1 * inv + bg.y;
    v0 = v0 > 0.f ? v0 : expm1f(v0);
    v1 = v1 > 0.f ? v1 : expm1f(v1);
    unsigned pk = (unsigned)f2b(v0) | ((unsigned)f2b(v1) << 16);
    *reinterpret_cast<unsigned*>((unsigned short*)agg + (long)d * HC + 2 * lane) = pk;
}

// ---------------- final: leaky(x2@W3+b3) -> softmax -> fp32 out (x2 in bf16) ----------------
__global__ __launch_bounds__(256) void k_final(const __hip_bfloat16* __restrict__ x2, const float* __restrict__ W3,
                                               const float* __restrict__ b3, float* __restrict__ out)
{
    __shared__ float w3s[128 * 10];
    __shared__ float b3s[10];
    int t = threadIdx.x;
    for (int i = t; i < 128 * 10; i += 256) w3s[i] = W3[i];
    if (t < 10) b3s[t] = b3[t];
    __syncthreads();
    int n = blockIdx.x * 256 + t;
    if (n >= NN) return;

    float l[10];
    #pragma unroll
    for (int j = 0; j < 10; ++j) l[j] = b3s[j];
    const uint4* row = reinterpret_cast<const uint4*>(x2 + (long)n * 128);
    #pragma unroll 4
    for (int c8 = 0; c8 < 16; ++c8) {
        uint4 v = row[c8];
        const unsigned w[4] = {v.x, v.y, v.z, v.w};
        #pragma unroll
        for (int u = 0; u < 4; ++u) {
            float f0 = __uint_as_float(w[u] << 16);
            float f1 = __uint_as_float(w[u] & 0xffff0000u);
            const float* wr = &w3s[(c8 * 8 + u * 2) * 10];
            #pragma unroll
            for (int j = 0; j < 10; ++j) l[j] += f0 * wr[j] + f1 * wr[10 + j];
        }
    }
    float m = -1e30f;
    #pragma unroll
    for (int j = 0; j < 10; ++j) {
        float v = l[j];
        v = v > 0.f ? v : 0.01f * v;
        l[j] = v;
        m = fmaxf(m, v);
    }
    float sum = 0.f;
    #pragma unroll
    for (int j = 0; j < 10; ++j) { l[j] = __expf(l[j] - m); sum += l[j]; }
    float inv = 1.f / sum;
    #pragma unroll
    for (int j = 0; j < 10; ++j) out[(long)n * 10 + j] = l[j] * inv;
}

extern "C" void kernel_launch(void* const* d_in, const int* in_sizes, int n_in,
                              void* d_out, int out_size, void* d_ws, size_t ws_size,
                              hipStream_t stream)
{
    const float* x       = (const float*)d_in[0];
    const int*   ei      = (const int*)d_in[1];
    const float* fb      = (const float*)d_in[2];
    const float* Wg      = (const float*)d_in[3];
    const float* bias_g  = (const float*)d_in[4];
    const float* att_src = (const float*)d_in[5];
    const float* att_dst = (const float*)d_in[6];
    const float* W1      = (const float*)d_in[7];
    const float* b1      = (const float*)d_in[8];
    const float* W2      = (const float*)d_in[9];
    const float* b2      = (const float*)d_in[10];
    const float* W3      = (const float*)d_in[11];
    const float* b3      = (const float*)d_in[12];
    float* out = (float*)d_out;
    float* ws = (float*)d_ws;

    // workspace layout (float units) — total 14,167,720 floats = 56.67 MB
    float* a_s = ws + 0;                                        //   200,000 [N,4]
    float* a_d = ws + 200000;                                   //   200,000 [N,4]
    __hip_bfloat16* fbWgT = (__hip_bfloat16*)(ws + 400000);     //   [128][544] bf16 (34,816 f)
    __hip_bfloat16* W1T   = (__hip_bfloat16*)(ws + 434816);     //   [256][128] bf16 (16,384 f)
    __hip_bfloat16* W2T   = (__hip_bfloat16*)(ws + 451200);     //   [128][256] bf16 (16,384 f)
    int* hist   = (int*)(ws + 467584);                          //    50,000 (cursor aliases)
    int* startA = (int*)(ws + 517584);                          //    50,004
    int* aux    = (int*)(ws + 567588);                          //       132
    int* sorted = (int*)(ws + 567720);                          //   800,000
    __hip_bfloat16* hbufB = (__hip_bfloat16*)(ws + 1367720);    //   [N,128] bf16 (3,200,000 f)
    __hip_bfloat16* aggB  = (__hip_bfloat16*)(ws + 4567720);    //   [N,128] bf16 (3,200,000 f)
    __hip_bfloat16* x1B   = (__hip_bfloat16*)(ws + 7767720);    //   [N,256] bf16 (6,400,000 f)
    int* cursor = hist;                                         //   alias (hist dead after scan1)
    __hip_bfloat16* x2B = hbufB;                                //   [N,128] bf16 over dead hbuf
    if (ws_size < (size_t)14167720 * sizeof(float)) return;     //   diagnostic: leaves out zeroed

    // zero fbWgT (for K-pad zeros) .. hist (contiguous region)
    hipMemsetAsync(ws + 400000, 0, (size_t)117584 * sizeof(float), stream);

    // fbWgT = (fb @ Wg)^T as bf16, zero-padded K 513->544
    gemm_k<2, float, float, __hip_bfloat16><<<dim3(9, 2), 256, 0, stream>>>(fb, Wg, fbWgT, NFR, HC, NMEL, nullptr);
    // W1T, W2T: transpose-convert weights
    k_trans<<<128, 256, 0, stream>>>(W1, W1T, 128, 256, 128);
    k_trans<<<128, 256, 0, stream>>>(W2, W2T, 256, 128, 256);

    // h = x @ fbWg   (64-row blocks, LDS-dbuf B, prefetched A)  [N,128]
    hgemm<<<(NN + 63) / 64, 256, 0, stream>>>(x, fbWgT, hbufB);

    // per-node attention coefficients
    k_att<<<(NN * 4 + 255) / 256, 256, 0, stream>>>(hbufB, att_src, att_dst, a_s, a_d);

    // CSR build
    k_hist<<<(EE + 255) / 256, 256, 0, stream>>>(ei, hist);
    k_scan1<<<98, 512, 0, stream>>>(hist, startA, aux);
    k_scan2<<<1, 128, 0, stream>>>(aux, 98);
    k_scan3<<<98, 512, 0, stream>>>(startA, cursor, aux);
    k_fill<<<(EE + 255) / 256, 256, 0, stream>>>(ei, cursor, sorted);

    // gather-aggregate: softmax + messages + bias + ELU -> agg bf16
    k_agg<<<(NN + 3) / 4, 256, 0, stream>>>(startA, sorted, a_s, a_d, hbufB, bias_g, aggB);

    const int GB = (NN / 16 + 3) / 4;   // 782 blocks of 4 waves (16-row strips)

    // x1 = leaky(agg @ W1 + b1)   [N,256] bf16 — two 128-col blocks (no VGPR spill)
    sgemm<8, 1><<<dim3(GB, 2), 256, 0, stream>>>(aggB, W1T, x1B, NN, 128, b1, 256);

    // x2 = leaky(x1 @ W2 + b2)    [N,128] bf16 (over dead hbuf)
    sgemm<8, 1><<<dim3(GB, 1), 256, 0, stream>>>(x1B, W2T, x2B, NN, 256, b2, 128);

    // out = softmax(leaky(x2 @ W3 + b3))
    k_final<<<(NN + 255) / 256, 256, 0, stream>>>(x2B, W3, b3, out);
}